// Round 12
// baseline (816.003 us; speedup 1.0000x reference)
//
#include <hip/hip_runtime.h>
#include <math.h>

// AttentionPooling: B=32 S=4096 E=1024 H=16 D=64
// scores[b,h,s] = (Wk_h^T q[b,h]).x[b,s]/8 ; ctx[b,h] = Wv_h (sum_s attn x[b,s]) + bv
// kfuse4-v2: SINGLE x read, half-tile double-buffered (2x32KB), spill-free.
// R12 changes vs R11 (counter-diagnosed): (1) #pragma unroll 2 on phase-A k-loop —
// full unroll hoisted 64 float4 p-loads (256 dest regs) -> VGPR 252 + ~118 MB scratch
// spill (WRITE_SIZE 160 MB vs 42 real); (2) __launch_bounds__(256,2) to pin 2 waves/EU
// so the 2-blocks/CU the 67 KB LDS permits are actually resident (R11 ran 1 block/CU,
// latency-bound lockstep: HBM 5%, VALU 21%).

constexpr int cB = 32, cS = 4096, cE = 1024, cH = 16, cD = 64, cNC = 16;

// ws layout in floats
constexpr size_t OFF_P    = 0;                     // B*H*E   = 524288
constexpr size_t OFF_C    = OFF_P + 524288;        // B*H     = 512
constexpr size_t OFF_Q    = OFF_C + 512;           // B*E     = 32768
constexpr size_t OFF_SC   = OFF_Q + 32768;         // B*H*S   = 2097152 masked scores
constexpr size_t OFF_SM   = OFF_SC + 2097152;      // B*H*NC  = 8192 chunk max
constexpr size_t OFF_SL   = OFF_SM + 8192;         // B*H*NC  = 8192 chunk expsum
constexpr size_t OFF_MF   = OFF_SL + 8192;         // B*H     = 512 row max
constexpr size_t OFF_IL   = OFF_MF + 512;          // B*H     = 512 inv rowsum
constexpr size_t OFF_CTX  = OFF_IL + 512;          // B*E     = 32768
constexpr size_t OFF_PART = OFF_CTX + 32768;       // B*NC*H*E = 8388608
constexpr size_t OFF_Y    = OFF_PART + 8388608;    // B*H*E   = 524288

__device__ inline float sel4(float a0, float a1, float a2, float a3, int i) {
  return i == 0 ? a0 : (i == 1 ? a1 : (i == 2 ? a2 : a3));
}

// ---------------- kgemm32: C[32, n-tile16] = A[32,1024] @ W^T rows + bias ------------
__global__ __launch_bounds__(256) void kgemm32(const float* __restrict__ A,
                                               size_t aRowStride, int aBlk,
                                               const float* __restrict__ Wm, int wRow0,
                                               const float* __restrict__ bias,
                                               float* __restrict__ C) {
  __shared__ float a_lds[32 * 1028];
  __shared__ float red[4][16][32];
  int tid = threadIdx.x;
  int bx = blockIdx.x;
  const float* abase = A + (aBlk ? ((size_t)(bx >> 2) * 1024) : (size_t)0);
#pragma unroll 4
  for (int j = 0; j < 32; ++j) {
    float4 v = *(const float4*)(abase + (size_t)j * aRowStride + (size_t)tid * 4);
    *(float4*)(a_lds + j * 1028 + tid * 4) = v;
  }
  __syncthreads();
  int wv = tid >> 6, lane = tid & 63;
  int ng = lane >> 4, bp = lane & 15;
  float acc[4][2];
#pragma unroll
  for (int j = 0; j < 4; ++j) { acc[j][0] = 0.f; acc[j][1] = 0.f; }
  const float* w0 = Wm + (size_t)(wRow0 + bx * 16 + ng * 4) * 1024;
#pragma unroll 4
  for (int i = 0; i < 64; ++i) {
    int e4 = wv * 64 + ((i + bp) & 63);
    float4 a0 = *(const float4*)(a_lds + (bp * 2 + 0) * 1028 + e4 * 4);
    float4 a1 = *(const float4*)(a_lds + (bp * 2 + 1) * 1028 + e4 * 4);
#pragma unroll
    for (int j = 0; j < 4; ++j) {
      float4 w4 = *(const float4*)(w0 + (size_t)j * 1024 + e4 * 4);
      acc[j][0] = fmaf(w4.x, a0.x, acc[j][0]); acc[j][0] = fmaf(w4.y, a0.y, acc[j][0]);
      acc[j][0] = fmaf(w4.z, a0.z, acc[j][0]); acc[j][0] = fmaf(w4.w, a0.w, acc[j][0]);
      acc[j][1] = fmaf(w4.x, a1.x, acc[j][1]); acc[j][1] = fmaf(w4.y, a1.y, acc[j][1]);
      acc[j][1] = fmaf(w4.z, a1.z, acc[j][1]); acc[j][1] = fmaf(w4.w, a1.w, acc[j][1]);
    }
  }
#pragma unroll
  for (int j = 0; j < 4; ++j) {
    red[wv][ng * 4 + j][bp * 2 + 0] = acc[j][0];
    red[wv][ng * 4 + j][bp * 2 + 1] = acc[j][1];
  }
  __syncthreads();
#pragma unroll
  for (int t = 0; t < 2; ++t) {
    int idx = t * 256 + tid;
    int n = idx >> 5, b = idx & 31;
    float s = red[0][n][b] + red[1][n][b] + red[2][n][b] + red[3][n][b] +
              bias[bx * 16 + n];
    C[(size_t)b * 1024 + bx * 16 + n] = s;
  }
}

// ---------------- kp_gemm: p[b,h,et*256+e] = 0.125 * sum_d Wk[h*64+d,e] q[b,h*64+d] ---
__global__ __launch_bounds__(256) void kp_gemm(const float* __restrict__ w,
                                               const float* __restrict__ bvec,
                                               const float* __restrict__ q,
                                               float* __restrict__ p,
                                               float* __restrict__ cb) {
  __shared__ float w_lds[64 * 260];
  __shared__ float q_lds[32 * 65];
  int h = blockIdx.x >> 2, et = blockIdx.x & 3;
  int tid = threadIdx.x;
#pragma unroll 4
  for (int j = 0; j < 16; ++j) {
    int idx = j * 256 + tid;
    int row = idx >> 6, c4 = idx & 63;
    float4 v = *(const float4*)(w + (size_t)(1024 + h * 64 + row) * 1024 + et * 256 + c4 * 4);
    *(float4*)(w_lds + row * 260 + c4 * 4) = v;
  }
#pragma unroll
  for (int jj = 0; jj < 2; ++jj) {
    int idx = jj * 256 + tid;
    int row = idx >> 4, c4 = idx & 15;
    float4 v = *(const float4*)(q + (size_t)row * 1024 + h * 64 + c4 * 4);
    *(float4*)(q_lds + row * 65 + c4 * 4) = v;
  }
  __syncthreads();
  int b = tid & 31, eg = tid >> 5;
  float4 acc[8];
#pragma unroll
  for (int j = 0; j < 8; ++j) acc[j] = make_float4(0.f, 0.f, 0.f, 0.f);
#pragma unroll 4
  for (int d = 0; d < 64; ++d) {
    float qv = q_lds[b * 65 + d];
#pragma unroll
    for (int j = 0; j < 8; ++j) {
      float4 wv4 = *(const float4*)(w_lds + d * 260 + eg * 32 + j * 4);
      acc[j].x = fmaf(wv4.x, qv, acc[j].x);
      acc[j].y = fmaf(wv4.y, qv, acc[j].y);
      acc[j].z = fmaf(wv4.z, qv, acc[j].z);
      acc[j].w = fmaf(wv4.w, qv, acc[j].w);
    }
  }
  float* pb = p + (size_t)(b * cH + h) * cE + et * 256 + eg * 32;
#pragma unroll
  for (int j = 0; j < 8; ++j) {
    float4 o = make_float4(acc[j].x * 0.125f, acc[j].y * 0.125f,
                           acc[j].z * 0.125f, acc[j].w * 0.125f);
    *(float4*)(pb + j * 4) = o;
  }
  if (et == 0 && tid < 32) {
    int bb = tid;
    float cacc = 0.f;
    for (int d = 0; d < 64; ++d)
      cacc = fmaf(q_lds[bb * 65 + d], bvec[1024 + h * 64 + d], cacc);
    cb[bb * cH + h] = 0.125f * cacc;
  }
}

// ---------------- kfuse4: single-x-read, half-tile double-buffered, spill-free -------
// grid 512 = B*16 chunks of 256 s; block 256 = 4 waves; 32 half-tiles of 8 s x 1024 e.
// Phase A: wave wv owns s rows {wv*2, wv*2+1}; lane = (hg = l>>4 -> 4 h, eg = l&15).
// Staging: thread (st_s = tid>>5 row 0..7, st_q = tid&31) holds rv8[8] f4.
__global__ __launch_bounds__(256, 2) void kfuse4(const float* __restrict__ x,
                                                 const float* __restrict__ p,
                                                 const float* __restrict__ cbv,
                                                 const int* __restrict__ mask,
                                                 float* __restrict__ scores,
                                                 float* __restrict__ statsM,
                                                 float* __restrict__ statsL,
                                                 float* __restrict__ part) {
  __shared__ __align__(16) float xt[2][8 * 1024];  // 2 x 32 KB, sigma-swizzled cols
  __shared__ __align__(16) float exl[8][20];       // ex[s][h], 80 B rows (16B-aligned)
  __shared__ float smax[4][16], ssum[4][16], scl[16];
  int bx = blockIdx.x;
  int b = bx >> 4, sc = bx & 15;
  int s0g = sc * 256;
  int tid = threadIdx.x;
  int wv = tid >> 6;
  int l = tid & 63;
  int hg = l >> 4, eg = l & 15;
  int st_s = tid >> 5, st_q = tid & 31;
  int sigB = (tid & ~15) | ((tid & 15) ^ ((tid >> 4) & 7));   // phase-B slot for col tid

  const float* xrow = x + ((size_t)b * cS + s0g) * cE;
  const float* pbase = p + (size_t)(b * cH + hg * 4) * cE;

  float m_run[4], l_run[4];
#pragma unroll
  for (int j = 0; j < 4; ++j) { m_run[j] = -3e38f; l_run[j] = 0.f; }
  float4 acc2[16];
#pragma unroll
  for (int h = 0; h < 16; ++h) acc2[h] = make_float4(0.f, 0.f, 0.f, 0.f);
  float4 cbl = *(const float4*)(cbv + b * cH + hg * 4);
  float cba[4] = {cbl.x, cbl.y, cbl.z, cbl.w};

  float4 rv[8];
  // prologue: stage ht=0 into buf0; leave rv = data(ht=1)
  {
    const float* src = xrow + (size_t)st_s * cE + st_q * 4;
#pragma unroll
    for (int i = 0; i < 8; ++i) rv[i] = *(const float4*)(src + i * 128);
#pragma unroll
    for (int i = 0; i < 8; ++i) {
      int c = st_q + 32 * i;
      int slot = (c & ~15) | ((c & 15) ^ ((2 * i + (st_q >> 4)) & 7));
      *(float4*)&xt[0][st_s * 1024 + slot * 4] = rv[i];
    }
    const float* src1 = xrow + (size_t)(8 + st_s) * cE + st_q * 4;
#pragma unroll
    for (int i = 0; i < 8; ++i) rv[i] = *(const float4*)(src1 + i * 128);
  }
  __syncthreads();

#pragma unroll 1
  for (int ht = 0; ht < 32; ++ht) {
    int cur = ht & 1;
    // step 1: ds_write rv (data of ht+1) into idle buffer
    if (ht + 1 < 32) {
#pragma unroll
      for (int i = 0; i < 8; ++i) {
        int c = st_q + 32 * i;
        int slot = (c & ~15) | ((c & 15) ^ ((2 * i + (st_q >> 4)) & 7));
        *(float4*)&xt[cur ^ 1][st_s * 1024 + slot * 4] = rv[i];
      }
    }
    // step 2: issue loads for ht+2 (consumed next iter; hidden under phases A/B)
    if (ht + 2 < 32) {
      const float* src = xrow + (size_t)((ht + 2) * 8 + st_s) * cE + st_q * 4;
#pragma unroll
      for (int i = 0; i < 8; ++i) rv[i] = *(const float4*)(src + i * 128);
    }

    // ---- phase A: scores for s = ht*8 + wv*2 + {0,1}, heads hg*4..+3 ----
    const float* bufp = &xt[cur][0];
    int r0 = wv * 2, r1 = wv * 2 + 1;
    float a0[4], a1[4];
#pragma unroll
    for (int h = 0; h < 4; ++h) { a0[h] = 0.f; a1[h] = 0.f; }
    // R12: unroll 2 (NOT full) — full unroll hoisted 64 float4 p-loads -> 252 VGPR + spill
#pragma unroll 2
    for (int k = 0; k < 16; ++k) {
      int slot = eg * 16 + (k ^ (eg & 7));           // holds true col eg*16+k
      float4 xv0 = *(const float4*)&bufp[r0 * 1024 + slot * 4];
      float4 xv1 = *(const float4*)&bufp[r1 * 1024 + slot * 4];
      float4 pv0 = *(const float4*)(pbase + 0 * cE + eg * 64 + k * 4);
      float4 pv1 = *(const float4*)(pbase + 1 * cE + eg * 64 + k * 4);
      float4 pv2 = *(const float4*)(pbase + 2 * cE + eg * 64 + k * 4);
      float4 pv3 = *(const float4*)(pbase + 3 * cE + eg * 64 + k * 4);
      float4 pa[4] = {pv0, pv1, pv2, pv3};
#pragma unroll
      for (int h = 0; h < 4; ++h) {
        a0[h] = fmaf(xv0.x, pa[h].x, a0[h]); a0[h] = fmaf(xv0.y, pa[h].y, a0[h]);
        a0[h] = fmaf(xv0.z, pa[h].z, a0[h]); a0[h] = fmaf(xv0.w, pa[h].w, a0[h]);
        a1[h] = fmaf(xv1.x, pa[h].x, a1[h]); a1[h] = fmaf(xv1.y, pa[h].y, a1[h]);
        a1[h] = fmaf(xv1.z, pa[h].z, a1[h]); a1[h] = fmaf(xv1.w, pa[h].w, a1[h]);
      }
    }
    // eg-reduce over 16 lanes
#pragma unroll
    for (int m = 1; m < 16; m <<= 1)
#pragma unroll
      for (int h = 0; h < 4; ++h) {
        a0[h] += __shfl_xor(a0[h], m);
        a1[h] += __shfl_xor(a1[h], m);
      }
    // bias + mask
    int2 mv = *(const int2*)(mask + (size_t)b * cS + s0g + ht * 8 + wv * 2);
    float vs0[4], vs1[4];
#pragma unroll
    for (int h = 0; h < 4; ++h) {
      vs0[h] = mv.x ? -1e30f : a0[h] + cba[h];
      vs1[h] = mv.y ? -1e30f : a1[h] + cba[h];
    }
    float tm[4];
#pragma unroll
    for (int h = 0; h < 4; ++h) tm[h] = fmaxf(vs0[h], vs1[h]);
    if (eg < 4) smax[wv][hg * 4 + eg] = sel4(tm[0], tm[1], tm[2], tm[3], eg);
    __syncthreads();   // bar1: smax ready

    float mnew[4], rs[4];
#pragma unroll
    for (int h = 0; h < 4; ++h) {
      int H = hg * 4 + h;
      float wm = fmaxf(fmaxf(smax[0][H], smax[1][H]), fmaxf(smax[2][H], smax[3][H]));
      mnew[h] = fmaxf(m_run[h], wm);
      rs[h] = __expf(m_run[h] - mnew[h]);
    }
    float e0h[4], e1h[4], psum[4];
#pragma unroll
    for (int h = 0; h < 4; ++h) {
      e0h[h] = __expf(vs0[h] - mnew[h]);
      e1h[h] = __expf(vs1[h] - mnew[h]);
      psum[h] = e0h[h] + e1h[h];
    }
    if (eg < 8) {
      int ssel = eg & 1, hsel = eg >> 1;
      float v0 = sel4(vs0[0], vs0[1], vs0[2], vs0[3], hsel);
      float v1 = sel4(vs1[0], vs1[1], vs1[2], vs1[3], hsel);
      float q0 = sel4(e0h[0], e0h[1], e0h[2], e0h[3], hsel);
      float q1 = sel4(e1h[0], e1h[1], e1h[2], e1h[3], hsel);
      int s_loc = wv * 2 + ssel;
      scores[(size_t)(b * cH + hg * 4 + hsel) * cS + s0g + ht * 8 + s_loc] =
          ssel ? v1 : v0;
      exl[s_loc][hg * 4 + hsel] = ssel ? q1 : q0;
    }
    if (eg < 4) {
      ssum[wv][hg * 4 + eg] = sel4(psum[0], psum[1], psum[2], psum[3], eg);
      if (wv == 0) scl[hg * 4 + eg] = sel4(rs[0], rs[1], rs[2], rs[3], eg);
    }
    __syncthreads();   // bar2: exl/ssum/scl ready (also publishes step-1 ds_writes)

#pragma unroll
    for (int h = 0; h < 4; ++h) {
      int H = hg * 4 + h;
      float ts = ssum[0][H] + ssum[1][H] + ssum[2][H] + ssum[3][H];
      l_run[h] = l_run[h] * rs[h] + ts;
      m_run[h] = mnew[h];
    }

    // ---- phase B: rescale + accumulate from resident half-tile ----
    {
      const float4* sc4 = (const float4*)scl;
      float4 s0 = sc4[0], s1 = sc4[1], s2 = sc4[2], s3 = sc4[3];
      float sca[16] = {s0.x, s0.y, s0.z, s0.w, s1.x, s1.y, s1.z, s1.w,
                       s2.x, s2.y, s2.z, s2.w, s3.x, s3.y, s3.z, s3.w};
#pragma unroll
      for (int h = 0; h < 16; ++h) {
        acc2[h].x *= sca[h]; acc2[h].y *= sca[h];
        acc2[h].z *= sca[h]; acc2[h].w *= sca[h];
      }
    }
#pragma unroll
    for (int s = 0; s < 8; ++s) {
      float4 xv = *(const float4*)&bufp[s * 1024 + sigB * 4];
      const float4* er = (const float4*)(&exl[s][0]);
      float4 e0 = er[0], e1 = er[1], e2 = er[2], e3 = er[3];
      float ea[16] = {e0.x, e0.y, e0.z, e0.w, e1.x, e1.y, e1.z, e1.w,
                      e2.x, e2.y, e2.z, e2.w, e3.x, e3.y, e3.z, e3.w};
#pragma unroll
      for (int h = 0; h < 16; ++h) {
        acc2[h].x = fmaf(ea[h], xv.x, acc2[h].x);
        acc2[h].y = fmaf(ea[h], xv.y, acc2[h].y);
        acc2[h].z = fmaf(ea[h], xv.z, acc2[h].z);
        acc2[h].w = fmaf(ea[h], xv.w, acc2[h].w);
      }
    }
    __syncthreads();   // bar3: phase B done; next iter may overwrite this buffer
  }

  // chunk stats (wave 0, one lane per h)
  if (tid < 64 && eg < 4) {
    int H = hg * 4 + eg;
    statsM[(size_t)(b * cH + H) * cNC + sc] = sel4(m_run[0], m_run[1], m_run[2], m_run[3], eg);
    statsL[(size_t)(b * cH + H) * cNC + sc] = sel4(l_run[0], l_run[1], l_run[2], l_run[3], eg);
  }
  // part
  float* pb = part + ((size_t)(b * cNC + sc) * cH) * cE + (size_t)tid * 4;
#pragma unroll
  for (int h = 0; h < 16; ++h) *(float4*)(pb + (size_t)h * cE) = acc2[h];
}

// ---------------- k5a: y[b,h,:] = (sum_ck wgt part) * iL; emit Mf/iLf ----------------
__global__ __launch_bounds__(256) void k5a_comb(const float* __restrict__ part,
                                                const float* __restrict__ statsM,
                                                const float* __restrict__ statsL,
                                                float* __restrict__ y,
                                                float* __restrict__ Mf,
                                                float* __restrict__ iLf) {
  int b = blockIdx.x >> 4, h = blockIdx.x & 15;
  int bh = b * cH + h;
  int tid = threadIdx.x;
  float M = -3e38f;
#pragma unroll
  for (int c = 0; c < cNC; ++c) M = fmaxf(M, statsM[bh * cNC + c]);
  float L = 0.f;
  float wgt[cNC];
#pragma unroll
  for (int c = 0; c < cNC; ++c) {
    wgt[c] = __expf(statsM[bh * cNC + c] - M);
    L += statsL[bh * cNC + c] * wgt[c];
  }
  float iL = 1.0f / L;
  if (tid == 0) { Mf[bh] = M; iLf[bh] = iL; }
  float4 a = make_float4(0.f, 0.f, 0.f, 0.f);
  const float* pb = part + (size_t)b * cNC * cH * cE + (size_t)h * cE + (size_t)tid * 4;
#pragma unroll
  for (int c = 0; c < cNC; ++c) {
    float4 v = *(const float4*)(pb + (size_t)c * cH * cE);
    a.x = fmaf(v.x, wgt[c], a.x); a.y = fmaf(v.y, wgt[c], a.y);
    a.z = fmaf(v.z, wgt[c], a.z); a.w = fmaf(v.w, wgt[c], a.w);
  }
  a.x *= iL; a.y *= iL; a.z *= iL; a.w *= iL;
  *(float4*)(y + (size_t)bh * cE + (size_t)tid * 4) = a;
}

// ---------------- kmean: attn_weights[b,0,s] = mean_h exp(score - M_h)*iL_h ----------
__global__ __launch_bounds__(256) void kmean(const float* __restrict__ scores,
                                             const float* __restrict__ Mf,
                                             const float* __restrict__ iLf,
                                             float* __restrict__ out) {
  int idx = blockIdx.x * 256 + threadIdx.x;
  int b = idx >> 12, s = idx & 4095;
  float sum = 0.f;
#pragma unroll
  for (int h = 0; h < cH; ++h) {
    float v = scores[(size_t)(b * cH + h) * cS + s];
    sum += __expf(v - Mf[b * cH + h]) * iLf[b * cH + h];
  }
  out[cB * cE + (size_t)b * cS + s] = sum * (1.0f / 16.0f);
}

extern "C" void kernel_launch(void* const* d_in, const int* in_sizes, int n_in,
                              void* d_out, int out_size, void* d_ws, size_t ws_size,
                              hipStream_t stream) {
  const float* x = (const float*)d_in[0];
  const int* mask = (const int*)d_in[1];
  const float* in_proj_w = (const float*)d_in[2];
  const float* in_proj_b = (const float*)d_in[3];
  const float* out_w = (const float*)d_in[4];
  const float* out_b = (const float*)d_in[5];
  float* out = (float*)d_out;
  float* W = (float*)d_ws;

  float* p = W + OFF_P;
  float* cb = W + OFF_C;
  float* q = W + OFF_Q;
  float* scores = W + OFF_SC;
  float* statsM = W + OFF_SM;
  float* statsL = W + OFF_SL;
  float* Mf = W + OFF_MF;
  float* iLf = W + OFF_IL;
  float* ctx = W + OFF_CTX;
  float* part = W + OFF_PART;
  float* y = W + OFF_Y;

  // q[32,1024] = x[:,0,:] @ Wq^T + bq
  kgemm32<<<64, 256, 0, stream>>>(x, (size_t)cS * cE, 0, in_proj_w, 0, in_proj_b, q);
  // p + cb (Wk rows 1024..2047)
  kp_gemm<<<64, 256, 0, stream>>>(in_proj_w, in_proj_b, q, p, cb);
  // fused single-x-read scores + stats + weighted partial sums
  kfuse4<<<512, 256, 0, stream>>>(x, p, cb, mask, scores, statsM, statsL, part);
  // combine chunks -> y, emit Mf/iLf
  k5a_comb<<<512, 256, 0, stream>>>(part, statsM, statsL, y, Mf, iLf);
  // ctx[32,1024] = y_h @ Wv_h^T + bv
  kgemm32<<<64, 256, 0, stream>>>(y, (size_t)cH * cE, 1, in_proj_w, 2048,
                                  in_proj_b + 2048, ctx);
  // attn-weights mean
  kmean<<<512, 256, 0, stream>>>(scores, Mf, iLf, out);
  // out[32,1024] = ctx @ out_w^T + out_b
  kgemm32<<<64, 256, 0, stream>>>(ctx, (size_t)cE, 0, out_w, 0, out_b, out);
}

// Round 13
// 300.065 us; speedup vs baseline: 2.7194x; 2.7194x over previous
//
#include <hip/hip_runtime.h>
#include <math.h>

// AttentionPooling: B=32 S=4096 E=1024 H=16 D=64
// scores[b,h,s] = (Wk_h^T q[b,h]).x[b,s]/8 ; ctx[b,h] = Wv_h (sum_s attn x[b,s]) + bv
// R13 = R8 revert (best: 301 us, passed twice). Single-x-read fused variants (R10-R12)
// falsified: need ~180 VGPR/thread spill-free AND >=2 blocks/CU simultaneously —
// register file can't provide both (R10: 537 MB spill @252; R11: 1 blk/CU lockstep,
// HBM 5%; R12: VGPR cap 128 -> accumulator spill, 550 MB writes).
// Structure: kfuse2 per (b, 256-s chunk): retiled score stage (2s x 8h waves, 2x LDS
// amp) + chunk softmax stats + warm weighted-sum re-read. Weight GEMMs batched over b
// (weights read once): kgemm32 (q / ctx / out), kp_gemm (p + cb).

constexpr int cB = 32, cS = 4096, cE = 1024, cH = 16, cD = 64, cNC = 16;

// ws layout in floats
constexpr size_t OFF_P    = 0;                     // B*H*E   = 524288
constexpr size_t OFF_C    = OFF_P + 524288;        // B*H     = 512
constexpr size_t OFF_Q    = OFF_C + 512;           // B*E     = 32768
constexpr size_t OFF_SC   = OFF_Q + 32768;         // B*H*S   = 2097152 masked scores
constexpr size_t OFF_SM   = OFF_SC + 2097152;      // B*H*NC  = 8192 chunk max
constexpr size_t OFF_SL   = OFF_SM + 8192;         // B*H*NC  = 8192 chunk expsum
constexpr size_t OFF_MF   = OFF_SL + 8192;         // B*H     = 512 row max
constexpr size_t OFF_IL   = OFF_MF + 512;          // B*H     = 512 inv rowsum
constexpr size_t OFF_CTX  = OFF_IL + 512;          // B*E     = 32768
constexpr size_t OFF_PART = OFF_CTX + 32768;       // B*NC*H*E = 8388608
constexpr size_t OFF_Y    = OFF_PART + 8388608;    // B*H*E   = 524288

__device__ inline float wave_max64(float v) {
#pragma unroll
  for (int m = 1; m < 64; m <<= 1) v = fmaxf(v, __shfl_xor(v, m));
  return v;
}
__device__ inline float wave_sum64(float v) {
#pragma unroll
  for (int m = 1; m < 64; m <<= 1) v += __shfl_xor(v, m);
  return v;
}

// ---------------- kgemm32: C[32, n-tile16] = A[32,1024] @ W^T rows + bias ------------
// grid 64 n-tiles of 16 W-rows. A staged whole in LDS ([32][1028], 131.6 KB); wave w
// owns K-range [w*256,+256); lane = (ng 0..3, bp 0..15) owns 4 n x 2 b; bp-rotation of
// the e4 index de-conflicts LDS A-reads; W global reads coalesced. 4-way K-reduce LDS.
__global__ __launch_bounds__(256) void kgemm32(const float* __restrict__ A,
                                               size_t aRowStride, int aBlk,
                                               const float* __restrict__ Wm, int wRow0,
                                               const float* __restrict__ bias,
                                               float* __restrict__ C) {
  __shared__ float a_lds[32 * 1028];
  __shared__ float red[4][16][32];
  int tid = threadIdx.x;
  int bx = blockIdx.x;
  const float* abase = A + (aBlk ? ((size_t)(bx >> 2) * 1024) : (size_t)0);

  // stage A: row j (=b), col tid*4
#pragma unroll 4
  for (int j = 0; j < 32; ++j) {
    float4 v = *(const float4*)(abase + (size_t)j * aRowStride + (size_t)tid * 4);
    *(float4*)(a_lds + j * 1028 + tid * 4) = v;
  }
  __syncthreads();

  int wv = tid >> 6, lane = tid & 63;
  int ng = lane >> 4, bp = lane & 15;
  float acc[4][2];
#pragma unroll
  for (int j = 0; j < 4; ++j) { acc[j][0] = 0.f; acc[j][1] = 0.f; }

  const float* w0 = Wm + (size_t)(wRow0 + bx * 16 + ng * 4) * 1024;
#pragma unroll 4
  for (int i = 0; i < 64; ++i) {
    int e4 = wv * 64 + ((i + bp) & 63);
    float4 a0 = *(const float4*)(a_lds + (bp * 2 + 0) * 1028 + e4 * 4);
    float4 a1 = *(const float4*)(a_lds + (bp * 2 + 1) * 1028 + e4 * 4);
#pragma unroll
    for (int j = 0; j < 4; ++j) {
      float4 w4 = *(const float4*)(w0 + (size_t)j * 1024 + e4 * 4);
      acc[j][0] = fmaf(w4.x, a0.x, acc[j][0]); acc[j][0] = fmaf(w4.y, a0.y, acc[j][0]);
      acc[j][0] = fmaf(w4.z, a0.z, acc[j][0]); acc[j][0] = fmaf(w4.w, a0.w, acc[j][0]);
      acc[j][1] = fmaf(w4.x, a1.x, acc[j][1]); acc[j][1] = fmaf(w4.y, a1.y, acc[j][1]);
      acc[j][1] = fmaf(w4.z, a1.z, acc[j][1]); acc[j][1] = fmaf(w4.w, a1.w, acc[j][1]);
    }
  }
#pragma unroll
  for (int j = 0; j < 4; ++j) {
    red[wv][ng * 4 + j][bp * 2 + 0] = acc[j][0];
    red[wv][ng * 4 + j][bp * 2 + 1] = acc[j][1];
  }
  __syncthreads();
#pragma unroll
  for (int t = 0; t < 2; ++t) {
    int idx = t * 256 + tid;
    int n = idx >> 5, b = idx & 31;
    float s = red[0][n][b] + red[1][n][b] + red[2][n][b] + red[3][n][b] +
              bias[bx * 16 + n];
    C[(size_t)b * 1024 + bx * 16 + n] = s;
  }
}

// ---------------- kp_gemm: p[b,h,et*256+e] = 0.125 * sum_d Wk[h*64+d,e] q[b,h*64+d] ---
// grid 64 = (h 16) x (e-tile 4 of 256). Wk tile + q slice staged; thread (b, eg) owns
// 1 b x 32 e. cb folded in (et==0 blocks). Wk read once across the grid.
__global__ __launch_bounds__(256) void kp_gemm(const float* __restrict__ w,
                                               const float* __restrict__ bvec,
                                               const float* __restrict__ q,
                                               float* __restrict__ p,
                                               float* __restrict__ cb) {
  __shared__ float w_lds[64 * 260];
  __shared__ float q_lds[32 * 65];
  int h = blockIdx.x >> 2, et = blockIdx.x & 3;
  int tid = threadIdx.x;
  // stage Wk tile [64 d][256 e]
#pragma unroll 4
  for (int j = 0; j < 16; ++j) {
    int idx = j * 256 + tid;
    int row = idx >> 6, c4 = idx & 63;
    float4 v = *(const float4*)(w + (size_t)(1024 + h * 64 + row) * 1024 + et * 256 + c4 * 4);
    *(float4*)(w_lds + row * 260 + c4 * 4) = v;
  }
  // stage q slice [32 b][64 d]
#pragma unroll
  for (int jj = 0; jj < 2; ++jj) {
    int idx = jj * 256 + tid;
    int row = idx >> 4, c4 = idx & 15;
    float4 v = *(const float4*)(q + (size_t)row * 1024 + h * 64 + c4 * 4);
    *(float4*)(q_lds + row * 65 + c4 * 4) = v;
  }
  __syncthreads();

  int b = tid & 31, eg = tid >> 5;   // eg 0..7, 32 e each
  float4 acc[8];
#pragma unroll
  for (int j = 0; j < 8; ++j) acc[j] = make_float4(0.f, 0.f, 0.f, 0.f);
#pragma unroll 4
  for (int d = 0; d < 64; ++d) {
    float qv = q_lds[b * 65 + d];
#pragma unroll
    for (int j = 0; j < 8; ++j) {
      float4 wv4 = *(const float4*)(w_lds + d * 260 + eg * 32 + j * 4);
      acc[j].x = fmaf(wv4.x, qv, acc[j].x);
      acc[j].y = fmaf(wv4.y, qv, acc[j].y);
      acc[j].z = fmaf(wv4.z, qv, acc[j].z);
      acc[j].w = fmaf(wv4.w, qv, acc[j].w);
    }
  }
  float* pb = p + (size_t)(b * cH + h) * cE + et * 256 + eg * 32;
#pragma unroll
  for (int j = 0; j < 8; ++j) {
    float4 o = make_float4(acc[j].x * 0.125f, acc[j].y * 0.125f,
                           acc[j].z * 0.125f, acc[j].w * 0.125f);
    *(float4*)(pb + j * 4) = o;
  }
  if (et == 0 && tid < 32) {
    int bb = tid;
    float cacc = 0.f;
    for (int d = 0; d < 64; ++d)
      cacc = fmaf(q_lds[bb * 65 + d], bvec[1024 + h * 64 + d], cacc);
    cb[bb * cH + h] = 0.125f * cacc;
  }
}

// ---------------- kfuse2: scores + chunk stats + weighted sum, one cold x-pass --------
// grid 512 = B*16 s-chunks of 256, block 256 = 4 waves.
// Stage 1 retiled: wave = (hg = wv>>1 -> h0 = hg*8, sg = wv&1 -> s-half); lane owns
// 2 consecutive s x 8 h; b64 LDS reads (2x amp). p scalar via uniform h0.
// Epilogue: combined-max handshake (2 barriers), ex table al[256][20].
// Stage 2: thread owns 4 e x 16 h, re-reads own chunk hottest-first.
__global__ __launch_bounds__(256) void kfuse2(const float* __restrict__ x,
                                              const float* __restrict__ p,
                                              const float* __restrict__ cbias,
                                              const int* __restrict__ mask,
                                              float* __restrict__ scores,
                                              float* __restrict__ statsM,
                                              float* __restrict__ statsL,
                                              float* __restrict__ part) {
  __shared__ __align__(16) float smem[16384];   // 64 KB xT dbuf; al overlays [0..5120)
  __shared__ float sml_m[4][8], sml_l[4][8];
  int bx = blockIdx.x;
  int b = bx >> 4, sc = bx & 15;
  int s_base = sc * 256;
  int tid = threadIdx.x;
  int wv = tid >> 6, lane = tid & 63;
  int sg = wv & 1, hg = wv >> 1;
  int h0 = __builtin_amdgcn_readfirstlane(hg * 8);
  float acc[2][8];
#pragma unroll
  for (int i = 0; i < 2; ++i)
#pragma unroll
    for (int j = 0; j < 8; ++j) acc[i][j] = 0.f;

  const float* xb = x + ((size_t)b * cS + s_base) * cE;
  const float* __restrict__ pu = p + (size_t)(b * cH + h0) * cE;

  float4 sv[8];
  int r_ = tid >> 3, c4_ = tid & 7;

  // prologue: stage kt=0 (transposed + f4-group swizzle)
#pragma unroll
  for (int i = 0; i < 8; ++i)
    sv[i] = *(const float4*)(xb + (size_t)(i * 32 + r_) * cE + c4_ * 4);
  {
    float* xd = smem;
#pragma unroll
    for (int i = 0; i < 8; ++i) {
      int r = i * 32 + r_;
      float vv[4] = {sv[i].x, sv[i].y, sv[i].z, sv[i].w};
#pragma unroll
      for (int j = 0; j < 4; ++j) {
        int e = c4_ * 4 + j;
        int f = (e ^ (e >> 4)) & 15;
        xd[e * 256 + ((((r >> 2) ^ f) << 2) | (r & 3))] = vv[j];
      }
    }
  }
  __syncthreads();

  int gbase = sg * 32 + (lane >> 1);    // f4-group of this lane's s-pair
  int goff = (lane & 1) << 1;           // offset within group
  for (int kt = 1; kt <= 32; ++kt) {
    if (kt < 32) {
#pragma unroll
      for (int i = 0; i < 8; ++i)
        sv[i] = *(const float4*)(xb + (size_t)(i * 32 + r_) * cE + kt * 32 + c4_ * 4);
    }
    {
      const float* xs = smem + ((kt - 1) & 1) * 8192;
      const int kb = (kt - 1) * 32;
#pragma unroll 8
      for (int e = 0; e < 32; ++e) {
        int f = (e ^ (e >> 4)) & 15;
        float2 xv = *(const float2*)&xs[e * 256 + (((gbase ^ f) << 2) | goff)];
        float p0 = pu[kb + e];
        float p1 = pu[cE + kb + e];
        float p2 = pu[2 * cE + kb + e];
        float p3 = pu[3 * cE + kb + e];
        float p4 = pu[4 * cE + kb + e];
        float p5 = pu[5 * cE + kb + e];
        float p6 = pu[6 * cE + kb + e];
        float p7 = pu[7 * cE + kb + e];
        float pa[8] = {p0, p1, p2, p3, p4, p5, p6, p7};
#pragma unroll
        for (int hj = 0; hj < 8; ++hj) {
          acc[0][hj] = fmaf(xv.x, pa[hj], acc[0][hj]);
          acc[1][hj] = fmaf(xv.y, pa[hj], acc[1][hj]);
        }
      }
    }
    if (kt < 32) {
      float* xd = smem + (kt & 1) * 8192;
#pragma unroll
      for (int i = 0; i < 8; ++i) {
        int r = i * 32 + r_;
        float vv[4] = {sv[i].x, sv[i].y, sv[i].z, sv[i].w};
#pragma unroll
        for (int j = 0; j < 4; ++j) {
          int e = c4_ * 4 + j;
          int f = (e ^ (e >> 4)) & 15;
          xd[e * 256 + ((((r >> 2) ^ f) << 2) | (r & 3))] = vv[j];
        }
      }
    }
    __syncthreads();
  }

  // ---- epilogue: bias, mask, scores, combined-max stats, ex table ----
  float* al = smem;   // [256][20], overlays dead xT
  int sl_loc = sg * 128 + lane * 2;          // chunk-local s of pair
  int sl = s_base + sl_loc;                  // global s
  float ca[8];
  {
    float4 c0 = *(const float4*)(cbias + b * cH + h0);
    float4 c1 = *(const float4*)(cbias + b * cH + h0 + 4);
    ca[0] = c0.x; ca[1] = c0.y; ca[2] = c0.z; ca[3] = c0.w;
    ca[4] = c1.x; ca[5] = c1.y; ca[6] = c1.z; ca[7] = c1.w;
  }
  int2 mv = *(const int2*)(mask + (size_t)b * cS + sl);
  float vs0[8], vs1[8];
#pragma unroll
  for (int hj = 0; hj < 8; ++hj) {
    float v0 = mv.x ? -1e30f : acc[0][hj] + ca[hj];
    float v1 = mv.y ? -1e30f : acc[1][hj] + ca[hj];
    vs0[hj] = v0; vs1[hj] = v1;
    float2 o = make_float2(v0, v1);
    *(float2*)(scores + (size_t)(b * cH + h0 + hj) * cS + sl) = o;
    float wm = wave_max64(fmaxf(v0, v1));
    if (lane == 0) sml_m[wv][hj] = wm;
  }
  __syncthreads();
#pragma unroll
  for (int hj = 0; hj < 8; ++hj) {
    float mh = fmaxf(sml_m[hg * 2][hj], sml_m[hg * 2 + 1][hj]);
    float e0 = __expf(vs0[hj] - mh);
    float e1 = __expf(vs1[hj] - mh);
    float ws = wave_sum64(e0 + e1);
    if (lane == 0) sml_l[wv][hj] = ws;
    al[(sl_loc + 0) * 20 + h0 + hj] = e0;
    al[(sl_loc + 1) * 20 + h0 + hj] = e1;
  }
  __syncthreads();
  if (tid < 16) {
    int h = tid, hg2 = h >> 3, hj = h & 7;
    float mh = fmaxf(sml_m[hg2 * 2][hj], sml_m[hg2 * 2 + 1][hj]);
    float L = sml_l[hg2 * 2][hj] + sml_l[hg2 * 2 + 1][hj];
    statsM[(size_t)(b * cH + h) * cNC + sc] = mh;
    statsL[(size_t)(b * cH + h) * cNC + sc] = L;
  }

  // ---- stage 2: weighted sum, hottest-first ----
  float4 acc2[16];
#pragma unroll
  for (int h = 0; h < cH; ++h) acc2[h] = make_float4(0.f, 0.f, 0.f, 0.f);
  const float* xg = xb + (size_t)tid * 4;
#pragma unroll 4
  for (int s = 255; s >= 0; --s) {
    float4 xv = *(const float4*)(xg + (size_t)s * cE);
    const float4* ar = (const float4*)(al + s * 20);
    float4 a0 = ar[0], a1 = ar[1], a2 = ar[2], a3 = ar[3];
    float aa[16] = {a0.x, a0.y, a0.z, a0.w, a1.x, a1.y, a1.z, a1.w,
                    a2.x, a2.y, a2.z, a2.w, a3.x, a3.y, a3.z, a3.w};
#pragma unroll
    for (int h = 0; h < cH; ++h) {
      acc2[h].x = fmaf(aa[h], xv.x, acc2[h].x);
      acc2[h].y = fmaf(aa[h], xv.y, acc2[h].y);
      acc2[h].z = fmaf(aa[h], xv.z, acc2[h].z);
      acc2[h].w = fmaf(aa[h], xv.w, acc2[h].w);
    }
  }
  float* pb = part + ((size_t)(b * cNC + sc) * cH) * cE + (size_t)tid * 4;
#pragma unroll
  for (int h = 0; h < cH; ++h) *(float4*)(pb + (size_t)h * cE) = acc2[h];
}

// ---------------- k5a: y[b,h,:] = (sum_ck wgt part) * iL; emit Mf/iLf ----------------
__global__ __launch_bounds__(256) void k5a_comb(const float* __restrict__ part,
                                                const float* __restrict__ statsM,
                                                const float* __restrict__ statsL,
                                                float* __restrict__ y,
                                                float* __restrict__ Mf,
                                                float* __restrict__ iLf) {
  int b = blockIdx.x >> 4, h = blockIdx.x & 15;
  int bh = b * cH + h;
  int tid = threadIdx.x;
  float M = -3e38f;
#pragma unroll
  for (int c = 0; c < cNC; ++c) M = fmaxf(M, statsM[bh * cNC + c]);
  float L = 0.f;
  float wgt[cNC];
#pragma unroll
  for (int c = 0; c < cNC; ++c) {
    wgt[c] = __expf(statsM[bh * cNC + c] - M);
    L += statsL[bh * cNC + c] * wgt[c];
  }
  float iL = 1.0f / L;
  if (tid == 0) { Mf[bh] = M; iLf[bh] = iL; }
  float4 a = make_float4(0.f, 0.f, 0.f, 0.f);
  const float* pb = part + (size_t)b * cNC * cH * cE + (size_t)h * cE + (size_t)tid * 4;
#pragma unroll
  for (int c = 0; c < cNC; ++c) {
    float4 v = *(const float4*)(pb + (size_t)c * cH * cE);
    a.x = fmaf(v.x, wgt[c], a.x); a.y = fmaf(v.y, wgt[c], a.y);
    a.z = fmaf(v.z, wgt[c], a.z); a.w = fmaf(v.w, wgt[c], a.w);
  }
  a.x *= iL; a.y *= iL; a.z *= iL; a.w *= iL;
  *(float4*)(y + (size_t)bh * cE + (size_t)tid * 4) = a;
}

// ---------------- kmean: attn_weights[b,0,s] = mean_h exp(score - M_h)*iL_h ----------
__global__ __launch_bounds__(256) void kmean(const float* __restrict__ scores,
                                             const float* __restrict__ Mf,
                                             const float* __restrict__ iLf,
                                             float* __restrict__ out) {
  int idx = blockIdx.x * 256 + threadIdx.x;
  int b = idx >> 12, s = idx & 4095;
  float sum = 0.f;
#pragma unroll
  for (int h = 0; h < cH; ++h) {
    float v = scores[(size_t)(b * cH + h) * cS + s];
    sum += __expf(v - Mf[b * cH + h]) * iLf[b * cH + h];
  }
  out[cB * cE + (size_t)b * cS + s] = sum * (1.0f / 16.0f);
}

extern "C" void kernel_launch(void* const* d_in, const int* in_sizes, int n_in,
                              void* d_out, int out_size, void* d_ws, size_t ws_size,
                              hipStream_t stream) {
  const float* x = (const float*)d_in[0];
  const int* mask = (const int*)d_in[1];
  const float* in_proj_w = (const float*)d_in[2];
  const float* in_proj_b = (const float*)d_in[3];
  const float* out_w = (const float*)d_in[4];
  const float* out_b = (const float*)d_in[5];
  float* out = (float*)d_out;
  float* W = (float*)d_ws;

  float* p = W + OFF_P;
  float* cb = W + OFF_C;
  float* q = W + OFF_Q;
  float* scores = W + OFF_SC;
  float* statsM = W + OFF_SM;
  float* statsL = W + OFF_SL;
  float* Mf = W + OFF_MF;
  float* iLf = W + OFF_IL;
  float* ctx = W + OFF_CTX;
  float* part = W + OFF_PART;
  float* y = W + OFF_Y;

  // q[32,1024] = x[:,0,:] @ Wq^T + bq   (Wq rows 0..1023)
  kgemm32<<<64, 256, 0, stream>>>(x, (size_t)cS * cE, 0, in_proj_w, 0, in_proj_b, q);
  // p + cb  (Wk rows 1024..2047)
  kp_gemm<<<64, 256, 0, stream>>>(in_proj_w, in_proj_b, q, p, cb);
  // fused scores + stats + weighted partial sums
  kfuse2<<<512, 256, 0, stream>>>(x, p, cb, mask, scores, statsM, statsL, part);
  // combine chunks -> y, emit Mf/iLf
  k5a_comb<<<512, 256, 0, stream>>>(part, statsM, statsL, y, Mf, iLf);
  // ctx[32,1024] = y_h @ Wv_h^T + bv    (Wv rows 2048..3071; per-block A = y[:,h,:])
  kgemm32<<<64, 256, 0, stream>>>(y, (size_t)cH * cE, 1, in_proj_w, 2048,
                                  in_proj_b + 2048, ctx);
  // attn-weights mean
  kmean<<<512, 256, 0, stream>>>(scores, Mf, iLf, out);
  // out[32,1024] = ctx @ out_w^T + out_b
  kgemm32<<<64, 256, 0, stream>>>(ctx, (size_t)cE, 0, out_w, 0, out_b, out);
}